// Round 3
// baseline (1089.004 us; speedup 1.0000x reference)
//
#include <hip/hip_runtime.h>
#include <math.h>

typedef unsigned short u16;
typedef __bf16 bf16x8 __attribute__((ext_vector_type(8)));
typedef float f32x4 __attribute__((ext_vector_type(4)));

#define MROWS 12608   // B*N = 64*197
#define NSEQ  197
#define NHEAD 12
#define DMODEL 768

__device__ __forceinline__ u16 f2bf(float f) {
    __bf16 h = (__bf16)f;                  // native v_cvt (RNE)
    return __builtin_bit_cast(u16, h);
}
__device__ __forceinline__ float bf2f(u16 v) { return __uint_as_float(((unsigned)v) << 16); }

// build a bf16x8 A/B fragment from 8 consecutive fp32 values
__device__ __forceinline__ bf16x8 cvt8(const float* p) {
    float4 a = *(const float4*)p;
    float4 b = *(const float4*)(p + 4);
    union { bf16x8 v; u16 s[8]; } t;
    t.s[0] = f2bf(a.x); t.s[1] = f2bf(a.y); t.s[2] = f2bf(a.z); t.s[3] = f2bf(a.w);
    t.s[4] = f2bf(b.x); t.s[5] = f2bf(b.y); t.s[6] = f2bf(b.z); t.s[7] = f2bf(b.w);
    return t.v;
}

// async 16B global -> LDS (HW: lds dest = wave-uniform base + lane*16)
__device__ __forceinline__ void g2l16(const u16* g, u16* l) {
    __builtin_amdgcn_global_load_lds((const __attribute__((address_space(1))) unsigned*)g,
                                     (__attribute__((address_space(3))) unsigned*)l,
                                     16, 0, 0);
}

// ---------------- layernorm: fp32 in -> bf16 out, one wave per row ----------
__global__ __launch_bounds__(256) void ln_rows(const float* x,
                                               const float* g,
                                               const float* bta,
                                               u16* o, int Mr) {
    int w = threadIdx.x >> 6, lane = threadIdx.x & 63;
    int row = blockIdx.x * 4 + w;
    if (row >= Mr) return;
    const float* xr = x + (size_t)row * DMODEL;
    float vals[12];
    for (int i = 0; i < 6; ++i) {
        float2 xx = *(const float2*)(xr + i * 128 + lane * 2);
        vals[2 * i] = xx.x; vals[2 * i + 1] = xx.y;
    }
    float s = 0.f;
    for (int i = 0; i < 12; ++i) s += vals[i];
    for (int off = 1; off < 64; off <<= 1) s += __shfl_xor(s, off, 64);
    float mu = s * (1.f / 768.f);
    float v2 = 0.f;
    for (int i = 0; i < 12; ++i) { float d = vals[i] - mu; v2 += d * d; }
    for (int off = 1; off < 64; off <<= 1) v2 += __shfl_xor(v2, off, 64);
    float rstd = rsqrtf(v2 * (1.f / 768.f) + 1e-5f);
    u16* orow = o + (size_t)row * DMODEL;
    for (int i = 0; i < 6; ++i) {
        int c = i * 128 + lane * 2;
        float2 gg = *(const float2*)(g + c);
        float2 bb = *(const float2*)(bta + c);
        float y0 = (vals[2 * i] - mu) * rstd * gg.x + bb.x;
        float y1 = (vals[2 * i + 1] - mu) * rstd * gg.y + bb.y;
        *(unsigned*)(orow + c) = (unsigned)f2bf(y0) | ((unsigned)f2bf(y1) << 16);
    }
}

// -------- weight transpose: dst[n][k] (bf16) = src[k][n] (fp32) -------------
__global__ __launch_bounds__(256) void wtrans(const float* __restrict__ src,
                                              u16* __restrict__ dst,
                                              int ldsrc, int lddst) {
    __shared__ float t[32][33];
    int c = threadIdx.x & 31, r0 = threadIdx.x >> 5;
    int k0 = blockIdx.x * 32, n0 = blockIdx.y * 32;
#pragma unroll
    for (int i = 0; i < 4; ++i)
        t[r0 + 8 * i][c] = src[(size_t)(k0 + r0 + 8 * i) * ldsrc + n0 + c];
    __syncthreads();
#pragma unroll
    for (int i = 0; i < 4; ++i)
        dst[(size_t)(n0 + r0 + 8 * i) * lddst + k0 + c] = f2bf(t[c][r0 + 8 * i]);
}

// ---- wave-private barrier-free GEMM core: C[64 x 128] per block -----------
// 4 waves (2m x 2n); each wave owns 32 A-rows + 64 B-cols, stages them into
// PRIVATE LDS (no __syncthreads at all). Double-buffered global_load_lds with
// counted s_waitcnt vmcnt(6) (T4: never drain mid-loop). T2 XOR swizzle:
// LDS slot s of row r holds k-chunk s ^ ((r>>1)&3); applied via inverse-
// permuted GLOBAL source (LDS dest stays linear per g2l16 HW constraint).
__device__ __forceinline__ void gemm_core64(
    const u16* __restrict__ A, const u16* __restrict__ BT,
    int M, int K, int lda, int ldb,
    u16 (*S)[4][3072],           // S[2][4][3072]
    f32x4 (&acc)[2][4])
{
    int tid = threadIdx.x, w = tid >> 6, lane = tid & 63;
    int row0 = blockIdx.x * 64, col0 = blockIdx.y * 128;
    int wm = w >> 1, wn = w & 1;
    int rsub = lane >> 2;                                   // staged row within 16-group
    int kch = ((lane & 3) ^ ((lane >> 3) & 3)) * 8;         // inverse-swizzled src chunk

    const u16* aG[2];
#pragma unroll
    for (int i = 0; i < 2; ++i) {
        int gr = row0 + wm * 32 + i * 16 + rsub;
        if (gr > M - 1) gr = M - 1;
        aG[i] = A + (size_t)gr * lda + kch;
    }
    const u16* bG[4];
#pragma unroll
    for (int j = 0; j < 4; ++j) {
        int gc = col0 + wn * 64 + j * 16 + rsub;
        bG[j] = BT + (size_t)gc * ldb + kch;
    }

    const f32x4 z = {0.f, 0.f, 0.f, 0.f};
#pragma unroll
    for (int i = 0; i < 2; ++i)
#pragma unroll
        for (int j = 0; j < 4; ++j) acc[i][j] = z;

    u16* sw0 = &S[0][w][0];
    u16* sw1 = &S[1][w][0];

    // prologue: stage k-step 0 into buffer 0
    g2l16(aG[0], sw0);        g2l16(aG[1], sw0 + 512);
    g2l16(bG[0], sw0 + 1024); g2l16(bG[1], sw0 + 1536);
    g2l16(bG[2], sw0 + 2048); g2l16(bG[3], sw0 + 2560);
    aG[0] += 32; aG[1] += 32;
    bG[0] += 32; bG[1] += 32; bG[2] += 32; bG[3] += 32;

    int lrow = lane & 15, lq = lane >> 4;
    int rof = (lq ^ ((lrow >> 1) & 3)) * 8;                 // swizzled read offset
    int nt = K >> 5;
    for (int t = 0; t < nt; ++t) {
        u16* cur = (t & 1) ? sw1 : sw0;
        if (t + 1 < nt) {
            u16* nx = (t & 1) ? sw0 : sw1;
            g2l16(aG[0], nx);        g2l16(aG[1], nx + 512);
            g2l16(bG[0], nx + 1024); g2l16(bG[1], nx + 1536);
            g2l16(bG[2], nx + 2048); g2l16(bG[3], nx + 2560);
            aG[0] += 32; aG[1] += 32;
            bG[0] += 32; bG[1] += 32; bG[2] += 32; bG[3] += 32;
            asm volatile("s_waitcnt vmcnt(6)" ::: "memory");   // cur's 6 done, nx's in flight
        } else {
            asm volatile("s_waitcnt vmcnt(0)" ::: "memory");
        }
        __builtin_amdgcn_sched_barrier(0);
        bf16x8 af[2], bfr[4];
#pragma unroll
        for (int mt = 0; mt < 2; ++mt)
            af[mt] = *(const bf16x8*)(cur + (mt * 16 + lrow) * 32 + rof);
#pragma unroll
        for (int n2 = 0; n2 < 4; ++n2)
            bfr[n2] = *(const bf16x8*)(cur + 1024 + (n2 * 16 + lrow) * 32 + rof);
#pragma unroll
        for (int mt = 0; mt < 2; ++mt)
#pragma unroll
            for (int n2 = 0; n2 < 4; ++n2)
                acc[mt][n2] = __builtin_amdgcn_mfma_f32_16x16x32_bf16(af[mt], bfr[n2], acc[mt][n2], 0, 0, 0);
    }
}

// generic epilogue wrapper: bias, scale, gelu, resid, fp32 and/or bf16 out
__global__ __launch_bounds__(256) void gemm_std(
    const u16* __restrict__ A, const u16* __restrict__ BT,
    float* Cf, u16* Cb, const float* bias, const float* resid,
    int M, int K, int lda, int ldb, int ldc, float scale, int do_gelu)
{
    __shared__ __align__(16) u16 S[2][4][3072];
    f32x4 acc[2][4];
    gemm_core64(A, BT, M, K, lda, ldb, S, acc);

    int tid = threadIdx.x, w = tid >> 6, lane = tid & 63;
    int row0 = blockIdx.x * 64, col0 = blockIdx.y * 128;
    int wmB = (w >> 1) * 32, wnB = (w & 1) * 64;
    int lrow = lane & 15, lq = lane >> 4;
#pragma unroll
    for (int mt = 0; mt < 2; ++mt) {
        int gmb = row0 + wmB + mt * 16 + lq * 4;
#pragma unroll
        for (int n2 = 0; n2 < 4; ++n2) {
            int gc = col0 + wnB + n2 * 16 + lrow;
            float bv = bias ? bias[gc] : 0.f;
            for (int r = 0; r < 4; ++r) {
                int gm = gmb + r;
                if (gm < M) {
                    float v0 = (acc[mt][n2][r] + bv) * scale;
                    if (do_gelu) v0 = 0.5f * v0 * (1.f + erff(v0 * 0.70710678118654752f));
                    if (resid) v0 += resid[(size_t)gm * ldc + gc];
                    if (Cf) Cf[(size_t)gm * ldc + gc] = v0;
                    if (Cb) Cb[(size_t)gm * ldc + gc] = f2bf(v0);
                }
            }
        }
    }
}

// fused QKV epilogue: N=2304 = [q | k | v]; q fp32*0.125, k fp32, v bf16
__global__ __launch_bounds__(256) void gemm_qkv(
    const u16* __restrict__ A, const u16* __restrict__ BT,
    float* qo, float* ko, u16* vo,
    const float* bq, const float* bk, const float* bvv, int M)
{
    __shared__ __align__(16) u16 S[2][4][3072];
    f32x4 acc[2][4];
    gemm_core64(A, BT, M, 768, 768, 768, S, acc);

    int tid = threadIdx.x, w = tid >> 6, lane = tid & 63;
    int row0 = blockIdx.x * 64, col0 = blockIdx.y * 128;
    int wmB = (w >> 1) * 32, wnB = (w & 1) * 64;
    int lrow = lane & 15, lq = lane >> 4;
#pragma unroll
    for (int mt = 0; mt < 2; ++mt) {
        int gmb = row0 + wmB + mt * 16 + lq * 4;
#pragma unroll
        for (int n2 = 0; n2 < 4; ++n2) {
            int gc = col0 + wnB + n2 * 16 + lrow;
            int j = gc / 768;                // uniform per block (col0 aligned to 128 | 768)
            int c = gc - j * 768;
            const float* bp = (j == 0) ? bq : (j == 1) ? bk : bvv;
            float bb = bp[c];
            for (int r = 0; r < 4; ++r) {
                int gm = gmb + r;
                if (gm < M) {
                    float v0 = acc[mt][n2][r] + bb;
                    size_t off = (size_t)gm * 768 + c;
                    if (j == 0)      qo[off] = v0 * 0.125f;
                    else if (j == 1) ko[off] = v0;
                    else             vo[off] = f2bf(v0);
                }
            }
        }
    }
}

// ---- fused attention: scores + softmax + probs-out + PV, one (b,h) slice ---
__global__ __launch_bounds__(256) void attn_fused(const float* q, const float* k,
                                                  const u16* v, float* attnw,
                                                  float* outf, u16* outb) {
    __shared__ __align__(16) u16 vT[64 * 224];      // [d][k] bf16, zero-padded k>=197
    __shared__ __align__(16) u16 P[4][16 * 224];    // per-wave [m][k], k ^ ((m>>2)<<3)
    int bid = blockIdx.x;
    int bh = bid >> 1, mb = bid & 1;
    int b = bh / NHEAD, hh = bh - b * NHEAD;
    int tid = threadIdx.x, w = tid >> 6, lane = tid & 63;
    int lrow = lane & 15, lq = lane >> 4;

    {
        int cg = (tid & 7) * 8;
        int rb = tid >> 3;
        for (int i = 0; i < 7; ++i) {
            int r = rb + i * 32;
            union { uint4 qv; u16 s[8]; } tmp;
            if (r < 197) {
                tmp.qv = *(const uint4*)(v + (size_t)(b * NSEQ + r) * DMODEL + hh * 64 + cg);
            } else {
                tmp.qv.x = tmp.qv.y = tmp.qv.z = tmp.qv.w = 0u;
            }
            for (int j = 0; j < 8; ++j) vT[(cg + j) * 224 + r] = tmp.s[j];
        }
    }
    u16* Pw = &P[w][0];
#pragma unroll
    for (int r = 0; r < 4; ++r) {
        int m = lq * 4 + r;
        Pw[m * 224 + ((208 + lrow) ^ (lq << 3))] = 0;
    }
    __syncthreads();   // vT ready

    size_t pbase = (size_t)bh * (NSEQ * NSEQ);
    int mstart = mb ? 7 : 0;
    int mcount = mb ? 6 : 7;

    for (int round = 0; round < 2; ++round) {
        int mi = round * 4 + w;
        if (mi >= mcount) continue;
        int mtile = mstart + mi;

        int gm0 = mtile * 16 + lrow; int gmq = gm0 > 196 ? 196 : gm0;
        const float* qrow = q + (size_t)(b * NSEQ + gmq) * DMODEL + hh * 64;
        bf16x8 aq0 = cvt8(qrow + lq * 8);
        bf16x8 aq1 = cvt8(qrow + 32 + lq * 8);

        f32x4 s[13];
#pragma unroll
        for (int nt = 0; nt < 13; ++nt) {
            int gn = nt * 16 + lrow; if (gn > 196) gn = 196;
            const float* krow = k + (size_t)(b * NSEQ + gn) * DMODEL + hh * 64;
            bf16x8 bk0 = cvt8(krow + lq * 8);
            bf16x8 bk1 = cvt8(krow + 32 + lq * 8);
            f32x4 a = {0.f, 0.f, 0.f, 0.f};
            a = __builtin_amdgcn_mfma_f32_16x16x32_bf16(aq0, bk0, a, 0, 0, 0);
            a = __builtin_amdgcn_mfma_f32_16x16x32_bf16(aq1, bk1, a, 0, 0, 0);
            s[nt] = a;
        }

        float rls[4];
        bool colbad = (lrow >= 5);
#pragma unroll
        for (int r = 0; r < 4; ++r) {
            float m1 = -1e30f;
#pragma unroll
            for (int nt = 0; nt < 12; ++nt) m1 = fmaxf(m1, s[nt][r]);
            m1 = fmaxf(m1, colbad ? -1e30f : s[12][r]);
            m1 = fmaxf(m1, __shfl_xor(m1, 1, 64));
            m1 = fmaxf(m1, __shfl_xor(m1, 2, 64));
            m1 = fmaxf(m1, __shfl_xor(m1, 4, 64));
            m1 = fmaxf(m1, __shfl_xor(m1, 8, 64));
            float sm = 0.f;
#pragma unroll
            for (int nt = 0; nt < 13; ++nt) {
                float e = __expf(s[nt][r] - m1);
                if (nt == 12 && colbad) e = 0.f;
                s[nt][r] = e;
                sm += e;
            }
            sm += __shfl_xor(sm, 1, 64);
            sm += __shfl_xor(sm, 2, 64);
            sm += __shfl_xor(sm, 4, 64);
            sm += __shfl_xor(sm, 8, 64);
            rls[r] = 1.f / sm;
        }

#pragma unroll
        for (int nt = 0; nt < 13; ++nt) {
            int gc = nt * 16 + lrow;
            bool cok = (gc < 197);
#pragma unroll
            for (int r = 0; r < 4; ++r) {
                float p = s[nt][r] * rls[r];
                s[nt][r] = p;
                int gm = mtile * 16 + lq * 4 + r;
                if (cok && gm < 197)
                    attnw[pbase + (size_t)gm * 197 + gc] = p;
            }
        }
#pragma unroll
        for (int nt = 0; nt < 13; ++nt) {
#pragma unroll
            for (int r = 0; r < 4; ++r) {
                int m = lq * 4 + r;
                Pw[m * 224 + ((nt * 16 + lrow) ^ (lq << 3))] = f2bf(s[nt][r]);
            }
        }

        f32x4 o[4];
        const f32x4 zf = {0.f, 0.f, 0.f, 0.f};
#pragma unroll
        for (int n2 = 0; n2 < 4; ++n2) o[n2] = zf;
#pragma unroll
        for (int ks = 0; ks < 7; ++ks) {
            bf16x8 af = *(const bf16x8*)(Pw + lrow * 224 + ((ks * 32 + lq * 8) ^ ((lrow >> 2) << 3)));
#pragma unroll
            for (int n2 = 0; n2 < 4; ++n2) {
                bf16x8 bv = *(const bf16x8*)(&vT[(n2 * 16 + lrow) * 224 + ks * 32 + lq * 8]);
                o[n2] = __builtin_amdgcn_mfma_f32_16x16x32_bf16(af, bv, o[n2], 0, 0, 0);
            }
        }
#pragma unroll
        for (int n2 = 0; n2 < 4; ++n2) {
            int gcol = hh * 64 + n2 * 16 + lrow;
#pragma unroll
            for (int r = 0; r < 4; ++r) {
                int gm = mtile * 16 + lq * 4 + r;
                if (gm < 197) {
                    size_t off = (size_t)(b * NSEQ + gm) * DMODEL + gcol;
                    outf[off] = o[n2][r];
                    outb[off] = f2bf(o[n2][r]);
                }
            }
        }
    }
}

extern "C" void kernel_launch(void* const* d_in, const int* in_sizes, int n_in,
                              void* d_out, int out_size, void* d_ws, size_t ws_size,
                              hipStream_t stream) {
    const float* x    = (const float*)d_in[0];
    const float* ln1g = (const float*)d_in[1];
    const float* ln1b = (const float*)d_in[2];
    const float* wq   = (const float*)d_in[3];
    const float* bq   = (const float*)d_in[4];
    const float* wk   = (const float*)d_in[5];
    const float* bk   = (const float*)d_in[6];
    const float* wv   = (const float*)d_in[7];
    const float* bv   = (const float*)d_in[8];
    const float* wo   = (const float*)d_in[9];
    const float* bo   = (const float*)d_in[10];
    const float* ln2g = (const float*)d_in[11];
    const float* ln2b = (const float*)d_in[12];
    const float* w1   = (const float*)d_in[13];
    const float* b1   = (const float*)d_in[14];
    const float* w2   = (const float*)d_in[15];
    const float* b2   = (const float*)d_in[16];

    float* out     = (float*)d_out;
    float* preproj = out;                 // output 0: 12608*768 fp32
    float* hidden  = out + 9682944;       // output 1: 12608*768 fp32
    float* attnw   = out + 19365888;      // output 2: 64*12*197*197 fp32

    u16* bufA = (u16*)d_ws;               // h -> attn_out(bf16) -> hsn
    u16* bufB = bufA + 9682944;           // v -> woT -> gelu chunk (+wT slots)

    // qkvT [2304][768] bf16 stashed in attnw region (dead until attn_fused)
    u16* qkvT = (u16*)attnw;

    long long tailElems = (long long)(ws_size >> 1) - 19365888LL;
    int CH; u16* w1T;
    if (tailElems >= 1179648LL)      { CH = 768; w1T = bufB + 9682944; }
    else if (tailElems >= 786432LL)  { CH = 512; w1T = bufB + 9682944; }
    else                             { CH = 512; w1T = bufB + 6455296; }
    u16* w2T = w1T + (size_t)CH * 768;
    int NCH = 3072 / CH;

    // LN1: x -> bufA (bf16)
    ln_rows<<<3152, 256, 0, stream>>>(x, ln1g, ln1b, bufA, MROWS);
    // transpose wq|wk|wv -> qkvT (bf16, [n][k])
    wtrans<<<dim3(24, 24), 256, 0, stream>>>(wq, qkvT,           768, 768);
    wtrans<<<dim3(24, 24), 256, 0, stream>>>(wk, qkvT + 589824,  768, 768);
    wtrans<<<dim3(24, 24), 256, 0, stream>>>(wv, qkvT + 1179648, 768, 768);
    // fused QKV: q(fp32*0.125)->preproj, k(fp32)->hidden, v(bf16)->bufB
    gemm_qkv<<<dim3(197, 18), 256, 0, stream>>>(bufA, qkvT, preproj, hidden, bufB,
                                                bq, bk, bv, MROWS);
    // fused attention: probs -> attnw (overwrites qkvT stash), out -> preproj + bufA
    attn_fused<<<1536, 256, 0, stream>>>(preproj, hidden, bufB, attnw, preproj, bufA);
    // woT into bufB (v dead), then out-proj + residual(x) -> hidden
    wtrans<<<dim3(24, 24), 256, 0, stream>>>(wo, bufB, 768, 768);
    gemm_std<<<dim3(197, 6), 256, 0, stream>>>(bufA, bufB, hidden, nullptr, bo, x,
                                               MROWS, 768, 768, 768, 768, 1.f, 0);
    // LN2: hidden -> bufA (bf16 hsn)
    ln_rows<<<3152, 256, 0, stream>>>(hidden, ln2g, ln2b, bufA, MROWS);
    // MLP in DFF chunks of CH
    for (int ci = 0; ci < NCH; ++ci) {
        wtrans<<<dim3(24, CH / 32), 256, 0, stream>>>(w1 + ci * CH, w1T, 3072, 768);
        wtrans<<<dim3(CH / 32, 24), 256, 0, stream>>>(w2 + (size_t)ci * CH * 768, w2T, 768, CH);
        gemm_std<<<dim3(197, CH / 128), 256, 0, stream>>>(
            bufA, w1T, nullptr, bufB, b1 + ci * CH, nullptr,
            MROWS, 768, 768, 768, CH, 1.f, 1);
        gemm_std<<<dim3(197, 6), 256, 0, stream>>>(
            bufB, w2T, hidden, nullptr, (ci == 0) ? b2 : nullptr, hidden,
            MROWS, CH, CH, CH, 768, 1.f, 0);
    }
}

// Round 4
// 922.053 us; speedup vs baseline: 1.1811x; 1.1811x over previous
//
#include <hip/hip_runtime.h>
#include <math.h>

typedef unsigned short u16;
typedef __bf16 bf16x8 __attribute__((ext_vector_type(8)));
typedef float f32x4 __attribute__((ext_vector_type(4)));

#define MROWS 12608   // B*N = 64*197
#define NSEQ  197
#define NHEAD 12
#define DMODEL 768

__device__ __forceinline__ u16 f2bf(float f) {
    __bf16 h = (__bf16)f;                  // native v_cvt (RNE)
    return __builtin_bit_cast(u16, h);
}
__device__ __forceinline__ float bf2f(u16 v) { return __uint_as_float(((unsigned)v) << 16); }

// build a bf16x8 A/B fragment from 8 consecutive fp32 values
__device__ __forceinline__ bf16x8 cvt8(const float* p) {
    float4 a = *(const float4*)p;
    float4 b = *(const float4*)(p + 4);
    union { bf16x8 v; u16 s[8]; } t;
    t.s[0] = f2bf(a.x); t.s[1] = f2bf(a.y); t.s[2] = f2bf(a.z); t.s[3] = f2bf(a.w);
    t.s[4] = f2bf(b.x); t.s[5] = f2bf(b.y); t.s[6] = f2bf(b.z); t.s[7] = f2bf(b.w);
    return t.v;
}

// async 16B global -> LDS (HW: lds dest = wave-uniform base + lane*16)
__device__ __forceinline__ void g2l16(const u16* g, u16* l) {
    __builtin_amdgcn_global_load_lds((const __attribute__((address_space(1))) unsigned*)g,
                                     (__attribute__((address_space(3))) unsigned*)l,
                                     16, 0, 0);
}

// XCD-ownership decode: grid = 104*ny blocks. xcd = bid&7 owns a FIXED
// contiguous chunk of the 99 M-blocks (13 for xcd<3, 12 else) for ALL y
// (y varies slowest) -> per-XCD A working set 2.4MB stays L2-resident.
__device__ __forceinline__ bool xcd_decode(int& x, int& y) {
    int bid = blockIdx.x;
    int c = bid & 7, j = bid >> 3;
    int cnt = (c < 3) ? 13 : 12;
    int x0  = (c < 3) ? c * 13 : 39 + (c - 3) * 12;
    y = j / 13;
    int xi = j - y * 13;
    if (xi >= cnt) return false;
    x = x0 + xi;
    return true;
}

// ---------------- layernorm: fp32 in -> bf16 out, one wave per row ----------
__global__ __launch_bounds__(256) void ln_rows(const float* x,
                                               const float* g,
                                               const float* bta,
                                               u16* o, int Mr) {
    int w = threadIdx.x >> 6, lane = threadIdx.x & 63;
    int row = blockIdx.x * 4 + w;
    if (row >= Mr) return;
    const float* xr = x + (size_t)row * DMODEL;
    float vals[12];
    for (int i = 0; i < 6; ++i) {
        float2 xx = *(const float2*)(xr + i * 128 + lane * 2);
        vals[2 * i] = xx.x; vals[2 * i + 1] = xx.y;
    }
    float s = 0.f;
    for (int i = 0; i < 12; ++i) s += vals[i];
    for (int off = 1; off < 64; off <<= 1) s += __shfl_xor(s, off, 64);
    float mu = s * (1.f / 768.f);
    float v2 = 0.f;
    for (int i = 0; i < 12; ++i) { float d = vals[i] - mu; v2 += d * d; }
    for (int off = 1; off < 64; off <<= 1) v2 += __shfl_xor(v2, off, 64);
    float rstd = rsqrtf(v2 * (1.f / 768.f) + 1e-5f);
    u16* orow = o + (size_t)row * DMODEL;
    for (int i = 0; i < 6; ++i) {
        int c = i * 128 + lane * 2;
        float2 gg = *(const float2*)(g + c);
        float2 bb = *(const float2*)(bta + c);
        float y0 = (vals[2 * i] - mu) * rstd * gg.x + bb.x;
        float y1 = (vals[2 * i + 1] - mu) * rstd * gg.y + bb.y;
        *(unsigned*)(orow + c) = (unsigned)f2bf(y0) | ((unsigned)f2bf(y1) << 16);
    }
}

// -------- weight transpose: dst[n][k] (bf16) = src[k][n] (fp32) -------------
__global__ __launch_bounds__(256) void wtrans(const float* __restrict__ src,
                                              u16* __restrict__ dst,
                                              int ldsrc, int lddst) {
    __shared__ float t[32][33];
    int c = threadIdx.x & 31, r0 = threadIdx.x >> 5;
    int k0 = blockIdx.x * 32, n0 = blockIdx.y * 32;
#pragma unroll
    for (int i = 0; i < 4; ++i)
        t[r0 + 8 * i][c] = src[(size_t)(k0 + r0 + 8 * i) * ldsrc + n0 + c];
    __syncthreads();
#pragma unroll
    for (int i = 0; i < 4; ++i)
        dst[(size_t)(n0 + r0 + 8 * i) * lddst + k0 + c] = f2bf(t[c][r0 + 8 * i]);
}

// ---- GEMM core: C[128 x 128] per block, 4 waves (2x2), wave = 64x64 -------
// T3-minimum 2-phase: stage(t+1) issued BEFORE consuming t; one barrier/step.
// T2 swizzle: LDS k-slot s of row r holds global chunk s ^ ((r>>1)&3),
// applied via inverse-permuted GLOBAL source (LDS dest linear, g2l16 HW).
__device__ __forceinline__ void gemm_core128(
    const u16* __restrict__ A, const u16* __restrict__ BT,
    int M, int K, int lda, int ldb, int x, int y,
    u16* aT, u16* bT, f32x4 (&acc)[4][4])
{
    int tid = threadIdx.x, w = tid >> 6, lane = tid & 63;
    int row0 = x * 128, col0 = y * 128;
    int rsub = lane >> 2;
    int kch = ((lane & 3) ^ ((rsub >> 1) & 3)) * 8;   // inverse-swizzled src chunk

    const u16* aG[2]; const u16* bG[2]; int lof[2];
#pragma unroll
    for (int i = 0; i < 2; ++i) {
        int g = (w * 2 + i) * 16 + rsub;              // 8 groups x 16 rows = 128
        int gr = row0 + g; if (gr > M - 1) gr = M - 1;
        aG[i] = A + (size_t)gr * lda + kch;
        bG[i] = BT + (size_t)(col0 + g) * ldb + kch;  // N always multiple of 128
        lof[i] = (w * 2 + i) * 512;
    }

    const f32x4 z = {0.f, 0.f, 0.f, 0.f};
#pragma unroll
    for (int i = 0; i < 4; ++i)
#pragma unroll
        for (int j = 0; j < 4; ++j) acc[i][j] = z;

    // prologue: stage K-step 0 into buffer 0
#pragma unroll
    for (int i = 0; i < 2; ++i) { g2l16(aG[i], aT + lof[i]); g2l16(bG[i], bT + lof[i]); }
    __syncthreads();

    int lrow = lane & 15, lq = lane >> 4;
    int rof = (lq ^ ((lrow >> 1) & 3)) * 8;           // swizzled read offset
    int wm = w >> 1, wn = w & 1;
    int nt = K >> 5;
    for (int t = 0; t < nt; ++t) {
        int cur = (t & 1) * 4096;
        if (t + 1 < nt) {
            int nx = 4096 - cur, ko = (t + 1) << 5;
#pragma unroll
            for (int i = 0; i < 2; ++i) {
                g2l16(aG[i] + ko, aT + nx + lof[i]);
                g2l16(bG[i] + ko, bT + nx + lof[i]);
            }
        }
        const u16* aC = aT + cur;
        const u16* bC = bT + cur;
        bf16x8 af[4], bfr[4];
#pragma unroll
        for (int mt = 0; mt < 4; ++mt)
            af[mt] = *(const bf16x8*)(aC + (wm * 64 + mt * 16 + lrow) * 32 + rof);
#pragma unroll
        for (int n2 = 0; n2 < 4; ++n2)
            bfr[n2] = *(const bf16x8*)(bC + (wn * 64 + n2 * 16 + lrow) * 32 + rof);
#pragma unroll
        for (int mt = 0; mt < 4; ++mt)
#pragma unroll
            for (int n2 = 0; n2 < 4; ++n2)
                acc[mt][n2] = __builtin_amdgcn_mfma_f32_16x16x32_bf16(af[mt], bfr[n2], acc[mt][n2], 0, 0, 0);
        __syncthreads();   // drains stage of t+1 (vmcnt) + protects buffer reuse
    }
}

// generic epilogue wrapper: bias, scale, gelu, resid, fp32 and/or bf16 out
__global__ __launch_bounds__(256) void gemm_std(
    const u16* __restrict__ A, const u16* __restrict__ BT,
    float* Cf, u16* Cb, const float* bias, const float* resid,
    int M, int K, int lda, int ldb, int ldc, float scale, int do_gelu)
{
    __shared__ __align__(16) u16 aT[2 * 4096];
    __shared__ __align__(16) u16 bT[2 * 4096];
    int x, y;
    if (!xcd_decode(x, y)) return;
    f32x4 acc[4][4];
    gemm_core128(A, BT, M, K, lda, ldb, x, y, aT, bT, acc);

    int tid = threadIdx.x, w = tid >> 6, lane = tid & 63;
    int row0 = x * 128, col0 = y * 128;
    int wmB = (w >> 1) * 64, wnB = (w & 1) * 64;
    int lrow = lane & 15, lq = lane >> 4;
#pragma unroll
    for (int mt = 0; mt < 4; ++mt) {
        int gmb = row0 + wmB + mt * 16 + lq * 4;
#pragma unroll
        for (int n2 = 0; n2 < 4; ++n2) {
            int gc = col0 + wnB + n2 * 16 + lrow;
            float bv = bias ? bias[gc] : 0.f;
            for (int r = 0; r < 4; ++r) {
                int gm = gmb + r;
                if (gm < M) {
                    float v0 = (acc[mt][n2][r] + bv) * scale;
                    if (do_gelu) v0 = 0.5f * v0 * (1.f + erff(v0 * 0.70710678118654752f));
                    if (resid) v0 += resid[(size_t)gm * ldc + gc];
                    if (Cf) Cf[(size_t)gm * ldc + gc] = v0;
                    if (Cb) Cb[(size_t)gm * ldc + gc] = f2bf(v0);
                }
            }
        }
    }
}

// fused QKV epilogue: N=2304 = [q | k | v]; q fp32*0.125, k fp32, v bf16
__global__ __launch_bounds__(256) void gemm_qkv(
    const u16* __restrict__ A, const u16* __restrict__ BT,
    float* qo, float* ko, u16* vo,
    const float* bq, const float* bk, const float* bvv, int M)
{
    __shared__ __align__(16) u16 aT[2 * 4096];
    __shared__ __align__(16) u16 bT[2 * 4096];
    int x, y;
    if (!xcd_decode(x, y)) return;
    f32x4 acc[4][4];
    gemm_core128(A, BT, M, 768, 768, 768, x, y, aT, bT, acc);

    int tid = threadIdx.x, w = tid >> 6, lane = tid & 63;
    int row0 = x * 128, col0 = y * 128;
    int wmB = (w >> 1) * 64, wnB = (w & 1) * 64;
    int lrow = lane & 15, lq = lane >> 4;
#pragma unroll
    for (int mt = 0; mt < 4; ++mt) {
        int gmb = row0 + wmB + mt * 16 + lq * 4;
#pragma unroll
        for (int n2 = 0; n2 < 4; ++n2) {
            int gc = col0 + wnB + n2 * 16 + lrow;
            int j = gc / 768;                // uniform per 128-block (128 | 768)
            int c = gc - j * 768;
            const float* bp = (j == 0) ? bq : (j == 1) ? bk : bvv;
            float bb = bp[c];
            for (int r = 0; r < 4; ++r) {
                int gm = gmb + r;
                if (gm < M) {
                    float v0 = acc[mt][n2][r] + bb;
                    size_t off = (size_t)gm * 768 + c;
                    if (j == 0)      qo[off] = v0 * 0.125f;
                    else if (j == 1) ko[off] = v0;
                    else             vo[off] = f2bf(v0);
                }
            }
        }
    }
}

// ---- fused attention: scores + softmax + probs-out + PV, one (b,h) slice ---
__global__ __launch_bounds__(256) void attn_fused(const float* q, const float* k,
                                                  const u16* v, float* attnw,
                                                  float* outf, u16* outb) {
    __shared__ __align__(16) u16 vT[64 * 224];      // [d][k] bf16, zero-padded k>=197
    __shared__ __align__(16) u16 P[4][16 * 224];    // per-wave [m][k], k ^ ((m>>2)<<3)
    int bid = blockIdx.x;
    int bh = bid >> 1, mb = bid & 1;
    int b = bh / NHEAD, hh = bh - b * NHEAD;
    int tid = threadIdx.x, w = tid >> 6, lane = tid & 63;
    int lrow = lane & 15, lq = lane >> 4;

    {
        int cg = (tid & 7) * 8;
        int rb = tid >> 3;
        for (int i = 0; i < 7; ++i) {
            int r = rb + i * 32;
            union { uint4 qv; u16 s[8]; } tmp;
            if (r < 197) {
                tmp.qv = *(const uint4*)(v + (size_t)(b * NSEQ + r) * DMODEL + hh * 64 + cg);
            } else {
                tmp.qv.x = tmp.qv.y = tmp.qv.z = tmp.qv.w = 0u;
            }
            for (int j = 0; j < 8; ++j) vT[(cg + j) * 224 + r] = tmp.s[j];
        }
    }
    u16* Pw = &P[w][0];
#pragma unroll
    for (int r = 0; r < 4; ++r) {
        int m = lq * 4 + r;
        Pw[m * 224 + ((208 + lrow) ^ (lq << 3))] = 0;
    }
    __syncthreads();   // vT ready

    size_t pbase = (size_t)bh * (NSEQ * NSEQ);
    int mstart = mb ? 7 : 0;
    int mcount = mb ? 6 : 7;

    for (int round = 0; round < 2; ++round) {
        int mi = round * 4 + w;
        if (mi >= mcount) continue;
        int mtile = mstart + mi;

        int gm0 = mtile * 16 + lrow; int gmq = gm0 > 196 ? 196 : gm0;
        const float* qrow = q + (size_t)(b * NSEQ + gmq) * DMODEL + hh * 64;
        bf16x8 aq0 = cvt8(qrow + lq * 8);
        bf16x8 aq1 = cvt8(qrow + 32 + lq * 8);

        f32x4 s[13];
#pragma unroll
        for (int nt = 0; nt < 13; ++nt) {
            int gn = nt * 16 + lrow; if (gn > 196) gn = 196;
            const float* krow = k + (size_t)(b * NSEQ + gn) * DMODEL + hh * 64;
            bf16x8 bk0 = cvt8(krow + lq * 8);
            bf16x8 bk1 = cvt8(krow + 32 + lq * 8);
            f32x4 a = {0.f, 0.f, 0.f, 0.f};
            a = __builtin_amdgcn_mfma_f32_16x16x32_bf16(aq0, bk0, a, 0, 0, 0);
            a = __builtin_amdgcn_mfma_f32_16x16x32_bf16(aq1, bk1, a, 0, 0, 0);
            s[nt] = a;
        }

        float rls[4];
        bool colbad = (lrow >= 5);
#pragma unroll
        for (int r = 0; r < 4; ++r) {
            float m1 = -1e30f;
#pragma unroll
            for (int nt = 0; nt < 12; ++nt) m1 = fmaxf(m1, s[nt][r]);
            m1 = fmaxf(m1, colbad ? -1e30f : s[12][r]);
            m1 = fmaxf(m1, __shfl_xor(m1, 1, 64));
            m1 = fmaxf(m1, __shfl_xor(m1, 2, 64));
            m1 = fmaxf(m1, __shfl_xor(m1, 4, 64));
            m1 = fmaxf(m1, __shfl_xor(m1, 8, 64));
            float sm = 0.f;
#pragma unroll
            for (int nt = 0; nt < 13; ++nt) {
                float e = __expf(s[nt][r] - m1);
                if (nt == 12 && colbad) e = 0.f;
                s[nt][r] = e;
                sm += e;
            }
            sm += __shfl_xor(sm, 1, 64);
            sm += __shfl_xor(sm, 2, 64);
            sm += __shfl_xor(sm, 4, 64);
            sm += __shfl_xor(sm, 8, 64);
            rls[r] = 1.f / sm;
        }

#pragma unroll
        for (int nt = 0; nt < 13; ++nt) {
            int gc = nt * 16 + lrow;
            bool cok = (gc < 197);
#pragma unroll
            for (int r = 0; r < 4; ++r) {
                float p = s[nt][r] * rls[r];
                s[nt][r] = p;
                int gm = mtile * 16 + lq * 4 + r;
                if (cok && gm < 197)
                    attnw[pbase + (size_t)gm * 197 + gc] = p;
            }
        }
#pragma unroll
        for (int nt = 0; nt < 13; ++nt) {
#pragma unroll
            for (int r = 0; r < 4; ++r) {
                int m = lq * 4 + r;
                Pw[m * 224 + ((nt * 16 + lrow) ^ (lq << 3))] = f2bf(s[nt][r]);
            }
        }

        f32x4 o[4];
        const f32x4 zf = {0.f, 0.f, 0.f, 0.f};
#pragma unroll
        for (int n2 = 0; n2 < 4; ++n2) o[n2] = zf;
#pragma unroll
        for (int ks = 0; ks < 7; ++ks) {
            bf16x8 af = *(const bf16x8*)(Pw + lrow * 224 + ((ks * 32 + lq * 8) ^ ((lrow >> 2) << 3)));
#pragma unroll
            for (int n2 = 0; n2 < 4; ++n2) {
                bf16x8 bv = *(const bf16x8*)(&vT[(n2 * 16 + lrow) * 224 + ks * 32 + lq * 8]);
                o[n2] = __builtin_amdgcn_mfma_f32_16x16x32_bf16(af, bv, o[n2], 0, 0, 0);
            }
        }
#pragma unroll
        for (int n2 = 0; n2 < 4; ++n2) {
            int gcol = hh * 64 + n2 * 16 + lrow;
#pragma unroll
            for (int r = 0; r < 4; ++r) {
                int gm = mtile * 16 + lq * 4 + r;
                if (gm < 197) {
                    size_t off = (size_t)(b * NSEQ + gm) * DMODEL + gcol;
                    outf[off] = o[n2][r];
                    outb[off] = f2bf(o[n2][r]);
                }
            }
        }
    }
}

extern "C" void kernel_launch(void* const* d_in, const int* in_sizes, int n_in,
                              void* d_out, int out_size, void* d_ws, size_t ws_size,
                              hipStream_t stream) {
    const float* x    = (const float*)d_in[0];
    const float* ln1g = (const float*)d_in[1];
    const float* ln1b = (const float*)d_in[2];
    const float* wq   = (const float*)d_in[3];
    const float* bq   = (const float*)d_in[4];
    const float* wk   = (const float*)d_in[5];
    const float* bk   = (const float*)d_in[6];
    const float* wv   = (const float*)d_in[7];
    const float* bv   = (const float*)d_in[8];
    const float* wo   = (const float*)d_in[9];
    const float* bo   = (const float*)d_in[10];
    const float* ln2g = (const float*)d_in[11];
    const float* ln2b = (const float*)d_in[12];
    const float* w1   = (const float*)d_in[13];
    const float* b1   = (const float*)d_in[14];
    const float* w2   = (const float*)d_in[15];
    const float* b2   = (const float*)d_in[16];

    float* out     = (float*)d_out;
    float* preproj = out;                 // output 0: 12608*768 fp32
    float* hidden  = out + 9682944;       // output 1: 12608*768 fp32
    float* attnw   = out + 19365888;      // output 2: 64*12*197*197 fp32

    u16* bufA = (u16*)d_ws;               // h -> attn_out(bf16) -> hsn
    u16* bufB = bufA + 9682944;           // v -> woT -> gelu chunk (+wT slots)

    // qkvT [2304][768] bf16 stashed in attnw region (dead until attn_fused)
    u16* qkvT = (u16*)attnw;

    long long tailElems = (long long)(ws_size >> 1) - 19365888LL;
    int CH; u16* w1T;
    if (tailElems >= 1179648LL)      { CH = 768; w1T = bufB + 9682944; }
    else if (tailElems >= 786432LL)  { CH = 512; w1T = bufB + 9682944; }
    else                             { CH = 512; w1T = bufB + 6455296; }
    u16* w2T = w1T + (size_t)CH * 768;
    int NCH = 3072 / CH;

    // LN1: x -> bufA (bf16)
    ln_rows<<<3152, 256, 0, stream>>>(x, ln1g, ln1b, bufA, MROWS);
    // transpose wq|wk|wv -> qkvT (bf16, [n][k])
    wtrans<<<dim3(24, 24), 256, 0, stream>>>(wq, qkvT,           768, 768);
    wtrans<<<dim3(24, 24), 256, 0, stream>>>(wk, qkvT + 589824,  768, 768);
    wtrans<<<dim3(24, 24), 256, 0, stream>>>(wv, qkvT + 1179648, 768, 768);
    // fused QKV: q(fp32*0.125)->preproj, k(fp32)->hidden, v(bf16)->bufB
    gemm_qkv<<<104 * 18, 256, 0, stream>>>(bufA, qkvT, preproj, hidden, bufB,
                                           bq, bk, bv, MROWS);
    // fused attention: probs -> attnw (overwrites qkvT stash), out -> preproj + bufA
    attn_fused<<<1536, 256, 0, stream>>>(preproj, hidden, bufB, attnw, preproj, bufA);
    // woT into bufB (v dead), then out-proj + residual(x) -> hidden
    wtrans<<<dim3(24, 24), 256, 0, stream>>>(wo, bufB, 768, 768);
    gemm_std<<<104 * 6, 256, 0, stream>>>(bufA, bufB, hidden, nullptr, bo, x,
                                          MROWS, 768, 768, 768, 768, 1.f, 0);
    // LN2: hidden -> bufA (bf16 hsn)
    ln_rows<<<3152, 256, 0, stream>>>(hidden, ln2g, ln2b, bufA, MROWS);
    // MLP in DFF chunks of CH
    for (int ci = 0; ci < NCH; ++ci) {
        wtrans<<<dim3(24, CH / 32), 256, 0, stream>>>(w1 + ci * CH, w1T, 3072, 768);
        wtrans<<<dim3(CH / 32, 24), 256, 0, stream>>>(w2 + (size_t)ci * CH * 768, w2T, 768, CH);
        gemm_std<<<104 * (CH / 128), 256, 0, stream>>>(
            bufA, w1T, nullptr, bufB, b1 + ci * CH, nullptr,
            MROWS, 768, 768, 768, CH, 1.f, 1);
        gemm_std<<<104 * 6, 256, 0, stream>>>(
            bufB, w2T, hidden, nullptr, (ci == 0) ? b2 : nullptr, hidden,
            MROWS, CH, CH, CH, 768, 1.f, 0);
    }
}

// Round 5
// 803.190 us; speedup vs baseline: 1.3558x; 1.1480x over previous
//
#include <hip/hip_runtime.h>
#include <math.h>

typedef unsigned short u16;
typedef __bf16 bf16x8 __attribute__((ext_vector_type(8)));
typedef float f32x4 __attribute__((ext_vector_type(4)));

#define MROWS 12608   // B*N = 64*197
#define NSEQ  197
#define NHEAD 12
#define DMODEL 768

__device__ __forceinline__ u16 f2bf(float f) {
    __bf16 h = (__bf16)f;                  // native v_cvt (RNE)
    return __builtin_bit_cast(u16, h);
}
__device__ __forceinline__ float bf2f(u16 v) { return __uint_as_float(((unsigned)v) << 16); }

// build a bf16x8 A/B fragment from 8 consecutive fp32 values
__device__ __forceinline__ bf16x8 cvt8(const float* p) {
    float4 a = *(const float4*)p;
    float4 b = *(const float4*)(p + 4);
    union { bf16x8 v; u16 s[8]; } t;
    t.s[0] = f2bf(a.x); t.s[1] = f2bf(a.y); t.s[2] = f2bf(a.z); t.s[3] = f2bf(a.w);
    t.s[4] = f2bf(b.x); t.s[5] = f2bf(b.y); t.s[6] = f2bf(b.z); t.s[7] = f2bf(b.w);
    return t.v;
}

// async 16B global -> LDS (HW: lds dest = wave-uniform base + lane*16)
__device__ __forceinline__ void g2l16(const u16* g, u16* l) {
    __builtin_amdgcn_global_load_lds((const __attribute__((address_space(1))) unsigned*)g,
                                     (__attribute__((address_space(3))) unsigned*)l,
                                     16, 0, 0);
}

// XCD-ownership decode: grid = 104*ny blocks. xcd = bid&7 owns a FIXED
// contiguous chunk of the 99 M-blocks (13 for xcd<3, 12 else) for ALL y
// (y varies slowest) -> per-XCD A working set 2.4MB stays L2-resident.
__device__ __forceinline__ bool xcd_decode(int& x, int& y) {
    int bid = blockIdx.x;
    int c = bid & 7, j = bid >> 3;
    int cnt = (c < 3) ? 13 : 12;
    int x0  = (c < 3) ? c * 13 : 39 + (c - 3) * 12;
    y = j / 13;
    int xi = j - y * 13;
    if (xi >= cnt) return false;
    x = x0 + xi;
    return true;
}

// ---------------- layernorm: fp32 in -> bf16 out, one wave per row ----------
__global__ __launch_bounds__(256) void ln_rows(const float* x,
                                               const float* g,
                                               const float* bta,
                                               u16* o, int Mr) {
    int w = threadIdx.x >> 6, lane = threadIdx.x & 63;
    int row = blockIdx.x * 4 + w;
    if (row >= Mr) return;
    const float* xr = x + (size_t)row * DMODEL;
    float vals[12];
    for (int i = 0; i < 6; ++i) {
        float2 xx = *(const float2*)(xr + i * 128 + lane * 2);
        vals[2 * i] = xx.x; vals[2 * i + 1] = xx.y;
    }
    float s = 0.f;
    for (int i = 0; i < 12; ++i) s += vals[i];
    for (int off = 1; off < 64; off <<= 1) s += __shfl_xor(s, off, 64);
    float mu = s * (1.f / 768.f);
    float v2 = 0.f;
    for (int i = 0; i < 12; ++i) { float d = vals[i] - mu; v2 += d * d; }
    for (int off = 1; off < 64; off <<= 1) v2 += __shfl_xor(v2, off, 64);
    float rstd = rsqrtf(v2 * (1.f / 768.f) + 1e-5f);
    u16* orow = o + (size_t)row * DMODEL;
    for (int i = 0; i < 6; ++i) {
        int c = i * 128 + lane * 2;
        float2 gg = *(const float2*)(g + c);
        float2 bb = *(const float2*)(bta + c);
        float y0 = (vals[2 * i] - mu) * rstd * gg.x + bb.x;
        float y1 = (vals[2 * i + 1] - mu) * rstd * gg.y + bb.y;
        *(unsigned*)(orow + c) = (unsigned)f2bf(y0) | ((unsigned)f2bf(y1) << 16);
    }
}

// -------- weight transpose: dst[n][k] (bf16) = src[k][n] (fp32) -------------
__global__ __launch_bounds__(256) void wtrans(const float* __restrict__ src,
                                              u16* __restrict__ dst,
                                              int ldsrc, int lddst) {
    __shared__ float t[32][33];
    int c = threadIdx.x & 31, r0 = threadIdx.x >> 5;
    int k0 = blockIdx.x * 32, n0 = blockIdx.y * 32;
#pragma unroll
    for (int i = 0; i < 4; ++i)
        t[r0 + 8 * i][c] = src[(size_t)(k0 + r0 + 8 * i) * ldsrc + n0 + c];
    __syncthreads();
#pragma unroll
    for (int i = 0; i < 4; ++i)
        dst[(size_t)(n0 + r0 + 8 * i) * lddst + k0 + c] = f2bf(t[c][r0 + 8 * i]);
}

// -------- ALL weight transposes in one dispatch (6912 blocks) ---------------
// [0,576)wq [576,1152)wk [1152,1728)wv [1728,2304)wo [2304,4608)w1 [4608,6912)w2
__global__ __launch_bounds__(256) void wtrans_all(
    const float* __restrict__ wq, const float* __restrict__ wk,
    const float* __restrict__ wv, const float* __restrict__ wo,
    const float* __restrict__ w1, const float* __restrict__ w2,
    u16* qkvT, u16* woT, u16* w1T, u16* w2T)
{
    int bid = blockIdx.x;
    const float* src; u16* dst; int ldsrc, lddst, k0, n0;
    if (bid < 2304) {
        int which = bid / 576, e = bid - which * 576;
        k0 = (e % 24) * 32; n0 = (e / 24) * 32;
        ldsrc = 768; lddst = 768;
        if (which == 0)      { src = wq; dst = qkvT; }
        else if (which == 1) { src = wk; dst = qkvT + 589824; }
        else if (which == 2) { src = wv; dst = qkvT + 1179648; }
        else                 { src = wo; dst = woT; }
    } else if (bid < 4608) {
        int e = bid - 2304;
        k0 = (e % 24) * 32; n0 = (e / 24) * 32;   // w1: [768][3072] -> [3072][768]
        src = w1; dst = w1T; ldsrc = 3072; lddst = 768;
    } else {
        int e = bid - 4608;
        k0 = (e % 96) * 32; n0 = (e / 96) * 32;   // w2: [3072][768] -> [768][3072]
        src = w2; dst = w2T; ldsrc = 768; lddst = 3072;
    }
    __shared__ float t[32][33];
    int c = threadIdx.x & 31, r0 = threadIdx.x >> 5;
#pragma unroll
    for (int i = 0; i < 4; ++i)
        t[r0 + 8 * i][c] = src[(size_t)(k0 + r0 + 8 * i) * ldsrc + n0 + c];
    __syncthreads();
#pragma unroll
    for (int i = 0; i < 4; ++i)
        dst[(size_t)(n0 + r0 + 8 * i) * lddst + k0 + c] = f2bf(t[c][r0 + 8 * i]);
}

// ---- GEMM core: C[128 x 128] per block, 4 waves (2x2), wave = 64x64 -------
// T3-minimum 2-phase: stage(t+1) issued BEFORE consuming t; one barrier/step.
// T2 swizzle: LDS k-slot s of row r holds global chunk s ^ ((r>>1)&3),
// applied via inverse-permuted GLOBAL source (LDS dest linear, g2l16 HW).
__device__ __forceinline__ void gemm_core128(
    const u16* __restrict__ A, const u16* __restrict__ BT,
    int M, int K, int lda, int ldb, int x, int y,
    u16* aT, u16* bT, f32x4 (&acc)[4][4])
{
    int tid = threadIdx.x, w = tid >> 6, lane = tid & 63;
    int row0 = x * 128, col0 = y * 128;
    int rsub = lane >> 2;
    int kch = ((lane & 3) ^ ((rsub >> 1) & 3)) * 8;   // inverse-swizzled src chunk

    const u16* aG[2]; const u16* bG[2]; int lof[2];
#pragma unroll
    for (int i = 0; i < 2; ++i) {
        int g = (w * 2 + i) * 16 + rsub;              // 8 groups x 16 rows = 128
        int gr = row0 + g; if (gr > M - 1) gr = M - 1;
        aG[i] = A + (size_t)gr * lda + kch;
        bG[i] = BT + (size_t)(col0 + g) * ldb + kch;  // N always multiple of 128
        lof[i] = (w * 2 + i) * 512;
    }

    const f32x4 z = {0.f, 0.f, 0.f, 0.f};
#pragma unroll
    for (int i = 0; i < 4; ++i)
#pragma unroll
        for (int j = 0; j < 4; ++j) acc[i][j] = z;

    // prologue: stage K-step 0 into buffer 0
#pragma unroll
    for (int i = 0; i < 2; ++i) { g2l16(aG[i], aT + lof[i]); g2l16(bG[i], bT + lof[i]); }
    __syncthreads();

    int lrow = lane & 15, lq = lane >> 4;
    int rof = (lq ^ ((lrow >> 1) & 3)) * 8;           // swizzled read offset
    int wm = w >> 1, wn = w & 1;
    int nt = K >> 5;
    for (int t = 0; t < nt; ++t) {
        int cur = (t & 1) * 4096;
        if (t + 1 < nt) {
            int nx = 4096 - cur, ko = (t + 1) << 5;
#pragma unroll
            for (int i = 0; i < 2; ++i) {
                g2l16(aG[i] + ko, aT + nx + lof[i]);
                g2l16(bG[i] + ko, bT + nx + lof[i]);
            }
        }
        const u16* aC = aT + cur;
        const u16* bC = bT + cur;
        bf16x8 af[4], bfr[4];
#pragma unroll
        for (int mt = 0; mt < 4; ++mt)
            af[mt] = *(const bf16x8*)(aC + (wm * 64 + mt * 16 + lrow) * 32 + rof);
#pragma unroll
        for (int n2 = 0; n2 < 4; ++n2)
            bfr[n2] = *(const bf16x8*)(bC + (wn * 64 + n2 * 16 + lrow) * 32 + rof);
#pragma unroll
        for (int mt = 0; mt < 4; ++mt)
#pragma unroll
            for (int n2 = 0; n2 < 4; ++n2)
                acc[mt][n2] = __builtin_amdgcn_mfma_f32_16x16x32_bf16(af[mt], bfr[n2], acc[mt][n2], 0, 0, 0);
        __syncthreads();   // drains stage of t+1 (vmcnt) + protects buffer reuse
    }
}

// generic epilogue wrapper: bias, scale, gelu, resid, fp32 and/or bf16 out
__global__ __launch_bounds__(256) void gemm_std(
    const u16* __restrict__ A, const u16* __restrict__ BT,
    float* Cf, u16* Cb, const float* bias, const float* resid,
    int M, int K, int lda, int ldb, int ldc, float scale, int do_gelu)
{
    __shared__ __align__(16) u16 aT[2 * 4096];
    __shared__ __align__(16) u16 bT[2 * 4096];
    int x, y;
    if (!xcd_decode(x, y)) return;
    f32x4 acc[4][4];
    gemm_core128(A, BT, M, K, lda, ldb, x, y, aT, bT, acc);

    int tid = threadIdx.x, w = tid >> 6, lane = tid & 63;
    int row0 = x * 128, col0 = y * 128;
    int wmB = (w >> 1) * 64, wnB = (w & 1) * 64;
    int lrow = lane & 15, lq = lane >> 4;
#pragma unroll
    for (int mt = 0; mt < 4; ++mt) {
        int gmb = row0 + wmB + mt * 16 + lq * 4;
#pragma unroll
        for (int n2 = 0; n2 < 4; ++n2) {
            int gc = col0 + wnB + n2 * 16 + lrow;
            float bv = bias ? bias[gc] : 0.f;
            for (int r = 0; r < 4; ++r) {
                int gm = gmb + r;
                if (gm < M) {
                    float v0 = (acc[mt][n2][r] + bv) * scale;
                    if (do_gelu) v0 = 0.5f * v0 * (1.f + erff(v0 * 0.70710678118654752f));
                    if (resid) v0 += resid[(size_t)gm * ldc + gc];
                    if (Cf) Cf[(size_t)gm * ldc + gc] = v0;
                    if (Cb) Cb[(size_t)gm * ldc + gc] = f2bf(v0);
                }
            }
        }
    }
}

// fused QKV epilogue: N=2304 = [q | k | v]; q fp32*0.125, k fp32, v bf16
__global__ __launch_bounds__(256) void gemm_qkv(
    const u16* __restrict__ A, const u16* __restrict__ BT,
    float* qo, float* ko, u16* vo,
    const float* bq, const float* bk, const float* bvv, int M)
{
    __shared__ __align__(16) u16 aT[2 * 4096];
    __shared__ __align__(16) u16 bT[2 * 4096];
    int x, y;
    if (!xcd_decode(x, y)) return;
    f32x4 acc[4][4];
    gemm_core128(A, BT, M, 768, 768, 768, x, y, aT, bT, acc);

    int tid = threadIdx.x, w = tid >> 6, lane = tid & 63;
    int row0 = x * 128, col0 = y * 128;
    int wmB = (w >> 1) * 64, wnB = (w & 1) * 64;
    int lrow = lane & 15, lq = lane >> 4;
#pragma unroll
    for (int mt = 0; mt < 4; ++mt) {
        int gmb = row0 + wmB + mt * 16 + lq * 4;
#pragma unroll
        for (int n2 = 0; n2 < 4; ++n2) {
            int gc = col0 + wnB + n2 * 16 + lrow;
            int j = gc / 768;                // uniform per 128-block (128 | 768)
            int c = gc - j * 768;
            const float* bp = (j == 0) ? bq : (j == 1) ? bk : bvv;
            float bb = bp[c];
            for (int r = 0; r < 4; ++r) {
                int gm = gmb + r;
                if (gm < M) {
                    float v0 = acc[mt][n2][r] + bb;
                    size_t off = (size_t)gm * 768 + c;
                    if (j == 0)      qo[off] = v0 * 0.125f;
                    else if (j == 1) ko[off] = v0;
                    else             vo[off] = f2bf(v0);
                }
            }
        }
    }
}

// ---- fused attention: scores + softmax + probs-out + PV, one (b,h) slice ---
__global__ __launch_bounds__(256) void attn_fused(const float* q, const float* k,
                                                  const u16* v, float* attnw,
                                                  float* outf, u16* outb) {
    __shared__ __align__(16) u16 vT[64 * 224];      // [d][k] bf16, zero-padded k>=197
    __shared__ __align__(16) u16 P[4][16 * 224];    // per-wave [m][k], k ^ ((m>>2)<<3)
    int bid = blockIdx.x;
    int bh = bid >> 1, mb = bid & 1;
    int b = bh / NHEAD, hh = bh - b * NHEAD;
    int tid = threadIdx.x, w = tid >> 6, lane = tid & 63;
    int lrow = lane & 15, lq = lane >> 4;

    {
        int cg = (tid & 7) * 8;
        int rb = tid >> 3;
        for (int i = 0; i < 7; ++i) {
            int r = rb + i * 32;
            union { uint4 qv; u16 s[8]; } tmp;
            if (r < 197) {
                tmp.qv = *(const uint4*)(v + (size_t)(b * NSEQ + r) * DMODEL + hh * 64 + cg);
            } else {
                tmp.qv.x = tmp.qv.y = tmp.qv.z = tmp.qv.w = 0u;
            }
            for (int j = 0; j < 8; ++j) vT[(cg + j) * 224 + r] = tmp.s[j];
        }
    }
    u16* Pw = &P[w][0];
#pragma unroll
    for (int r = 0; r < 4; ++r) {
        int m = lq * 4 + r;
        Pw[m * 224 + ((208 + lrow) ^ (lq << 3))] = 0;
    }
    __syncthreads();   // vT ready

    size_t pbase = (size_t)bh * (NSEQ * NSEQ);
    int mstart = mb ? 7 : 0;
    int mcount = mb ? 6 : 7;

    for (int round = 0; round < 2; ++round) {
        int mi = round * 4 + w;
        if (mi >= mcount) continue;
        int mtile = mstart + mi;

        int gm0 = mtile * 16 + lrow; int gmq = gm0 > 196 ? 196 : gm0;
        const float* qrow = q + (size_t)(b * NSEQ + gmq) * DMODEL + hh * 64;
        bf16x8 aq0 = cvt8(qrow + lq * 8);
        bf16x8 aq1 = cvt8(qrow + 32 + lq * 8);

        f32x4 s[13];
#pragma unroll
        for (int nt = 0; nt < 13; ++nt) {
            int gn = nt * 16 + lrow; if (gn > 196) gn = 196;
            const float* krow = k + (size_t)(b * NSEQ + gn) * DMODEL + hh * 64;
            bf16x8 bk0 = cvt8(krow + lq * 8);
            bf16x8 bk1 = cvt8(krow + 32 + lq * 8);
            f32x4 a = {0.f, 0.f, 0.f, 0.f};
            a = __builtin_amdgcn_mfma_f32_16x16x32_bf16(aq0, bk0, a, 0, 0, 0);
            a = __builtin_amdgcn_mfma_f32_16x16x32_bf16(aq1, bk1, a, 0, 0, 0);
            s[nt] = a;
        }

        float rls[4];
        bool colbad = (lrow >= 5);
#pragma unroll
        for (int r = 0; r < 4; ++r) {
            float m1 = -1e30f;
#pragma unroll
            for (int nt = 0; nt < 12; ++nt) m1 = fmaxf(m1, s[nt][r]);
            m1 = fmaxf(m1, colbad ? -1e30f : s[12][r]);
            m1 = fmaxf(m1, __shfl_xor(m1, 1, 64));
            m1 = fmaxf(m1, __shfl_xor(m1, 2, 64));
            m1 = fmaxf(m1, __shfl_xor(m1, 4, 64));
            m1 = fmaxf(m1, __shfl_xor(m1, 8, 64));
            float sm = 0.f;
#pragma unroll
            for (int nt = 0; nt < 13; ++nt) {
                float e = __expf(s[nt][r] - m1);
                if (nt == 12 && colbad) e = 0.f;
                s[nt][r] = e;
                sm += e;
            }
            sm += __shfl_xor(sm, 1, 64);
            sm += __shfl_xor(sm, 2, 64);
            sm += __shfl_xor(sm, 4, 64);
            sm += __shfl_xor(sm, 8, 64);
            rls[r] = 1.f / sm;
        }

#pragma unroll
        for (int nt = 0; nt < 13; ++nt) {
            int gc = nt * 16 + lrow;
            bool cok = (gc < 197);
#pragma unroll
            for (int r = 0; r < 4; ++r) {
                float p = s[nt][r] * rls[r];
                s[nt][r] = p;
                int gm = mtile * 16 + lq * 4 + r;
                if (cok && gm < 197)
                    attnw[pbase + (size_t)gm * 197 + gc] = p;
            }
        }
#pragma unroll
        for (int nt = 0; nt < 13; ++nt) {
#pragma unroll
            for (int r = 0; r < 4; ++r) {
                int m = lq * 4 + r;
                Pw[m * 224 + ((nt * 16 + lrow) ^ (lq << 3))] = f2bf(s[nt][r]);
            }
        }

        f32x4 o[4];
        const f32x4 zf = {0.f, 0.f, 0.f, 0.f};
#pragma unroll
        for (int n2 = 0; n2 < 4; ++n2) o[n2] = zf;
#pragma unroll
        for (int ks = 0; ks < 7; ++ks) {
            bf16x8 af = *(const bf16x8*)(Pw + lrow * 224 + ((ks * 32 + lq * 8) ^ ((lrow >> 2) << 3)));
#pragma unroll
            for (int n2 = 0; n2 < 4; ++n2) {
                bf16x8 bv = *(const bf16x8*)(&vT[(n2 * 16 + lrow) * 224 + ks * 32 + lq * 8]);
                o[n2] = __builtin_amdgcn_mfma_f32_16x16x32_bf16(af, bv, o[n2], 0, 0, 0);
            }
        }
#pragma unroll
        for (int n2 = 0; n2 < 4; ++n2) {
            int gcol = hh * 64 + n2 * 16 + lrow;
#pragma unroll
            for (int r = 0; r < 4; ++r) {
                int gm = mtile * 16 + lq * 4 + r;
                if (gm < 197) {
                    size_t off = (size_t)(b * NSEQ + gm) * DMODEL + gcol;
                    outf[off] = o[n2][r];
                    outb[off] = f2bf(o[n2][r]);
                }
            }
        }
    }
}

extern "C" void kernel_launch(void* const* d_in, const int* in_sizes, int n_in,
                              void* d_out, int out_size, void* d_ws, size_t ws_size,
                              hipStream_t stream) {
    const float* x    = (const float*)d_in[0];
    const float* ln1g = (const float*)d_in[1];
    const float* ln1b = (const float*)d_in[2];
    const float* wq   = (const float*)d_in[3];
    const float* bq   = (const float*)d_in[4];
    const float* wk   = (const float*)d_in[5];
    const float* bk   = (const float*)d_in[6];
    const float* wv   = (const float*)d_in[7];
    const float* bv   = (const float*)d_in[8];
    const float* wo   = (const float*)d_in[9];
    const float* bo   = (const float*)d_in[10];
    const float* ln2g = (const float*)d_in[11];
    const float* ln2b = (const float*)d_in[12];
    const float* w1   = (const float*)d_in[13];
    const float* b1   = (const float*)d_in[14];
    const float* w2   = (const float*)d_in[15];
    const float* b2   = (const float*)d_in[16];

    float* out     = (float*)d_out;
    float* preproj = out;                 // output 0: 12608*768 fp32
    float* hidden  = out + 9682944;       // output 1: 12608*768 fp32
    float* attnw   = out + 19365888;      // output 2: 64*12*197*197 fp32

    u16* bufA = (u16*)d_ws;               // h -> attn_out(bf16) -> hsn
    u16* bufB = bufA + 9682944;           // v
    u16* qkvT = (u16*)attnw;              // qkv^T stash (attnw dead until attn)

    long long tailElems = (long long)(ws_size >> 1) - 19365888LL;
    u16* tail = bufB + 9682944;

    // LN1: x -> bufA (bf16)
    ln_rows<<<3152, 256, 0, stream>>>(x, ln1g, ln1b, bufA, MROWS);

    if (tailElems >= 44015616LL) {
        // ---------- big-workspace path: all transposes in 1 dispatch, un-chunked MLP
        u16* woT  = tail;                       //   589824
        u16* w1T  = woT + 589824;               // 2 359 296
        u16* w2T  = w1T + 2359296;              // 2 359 296
        u16* gelu = w2T + 2359296;              // 38 707 200 (12608 x 3072 bf16)

        wtrans_all<<<6912, 256, 0, stream>>>(wq, wk, wv, wo, w1, w2,
                                             qkvT, woT, w1T, w2T);
        // fused QKV: q(fp32*0.125)->preproj, k(fp32)->hidden, v(bf16)->bufB
        gemm_qkv<<<104 * 18, 256, 0, stream>>>(bufA, qkvT, preproj, hidden, bufB,
                                               bq, bk, bv, MROWS);
        // fused attention: probs -> attnw, out -> preproj (fp32) + bufA (bf16)
        attn_fused<<<1536, 256, 0, stream>>>(preproj, hidden, bufB, attnw, preproj, bufA);
        // out-proj + residual(x) -> hidden
        gemm_std<<<104 * 6, 256, 0, stream>>>(bufA, woT, hidden, nullptr, bo, x,
                                              MROWS, 768, 768, 768, 768, 1.f, 0);
        // LN2: hidden -> bufA
        ln_rows<<<3152, 256, 0, stream>>>(hidden, ln2g, ln2b, bufA, MROWS);
        // MLP: one N=3072 gelu GEMM, one K=3072 GEMM (+bias, +resid)
        gemm_std<<<104 * 24, 256, 0, stream>>>(bufA, w1T, nullptr, gelu, b1, nullptr,
                                               MROWS, 768, 768, 768, 3072, 1.f, 1);
        gemm_std<<<104 * 6, 256, 0, stream>>>(gelu, w2T, hidden, nullptr, b2, hidden,
                                              MROWS, 3072, 3072, 3072, 768, 1.f, 0);
    } else {
        // ---------- fallback: round-4 chunked path (small workspace)
        int CH; u16* w1T;
        if (tailElems >= 1179648LL)      { CH = 768; w1T = tail; }
        else if (tailElems >= 786432LL)  { CH = 512; w1T = tail; }
        else                             { CH = 512; w1T = bufB + 6455296; }
        u16* w2T = w1T + (size_t)CH * 768;
        int NCH = 3072 / CH;

        wtrans<<<dim3(24, 24), 256, 0, stream>>>(wq, qkvT,           768, 768);
        wtrans<<<dim3(24, 24), 256, 0, stream>>>(wk, qkvT + 589824,  768, 768);
        wtrans<<<dim3(24, 24), 256, 0, stream>>>(wv, qkvT + 1179648, 768, 768);
        gemm_qkv<<<104 * 18, 256, 0, stream>>>(bufA, qkvT, preproj, hidden, bufB,
                                               bq, bk, bv, MROWS);
        attn_fused<<<1536, 256, 0, stream>>>(preproj, hidden, bufB, attnw, preproj, bufA);
        wtrans<<<dim3(24, 24), 256, 0, stream>>>(wo, bufB, 768, 768);
        gemm_std<<<104 * 6, 256, 0, stream>>>(bufA, bufB, hidden, nullptr, bo, x,
                                              MROWS, 768, 768, 768, 768, 1.f, 0);
        ln_rows<<<3152, 256, 0, stream>>>(hidden, ln2g, ln2b, bufA, MROWS);
        for (int ci = 0; ci < NCH; ++ci) {
            wtrans<<<dim3(24, CH / 32), 256, 0, stream>>>(w1 + ci * CH, w1T, 3072, 768);
            wtrans<<<dim3(CH / 32, 24), 256, 0, stream>>>(w2 + (size_t)ci * CH * 768, w2T, 768, CH);
            gemm_std<<<104 * (CH / 128), 256, 0, stream>>>(
                bufA, w1T, nullptr, bufB, b1 + ci * CH, nullptr,
                MROWS, 768, 768, 768, CH, 1.f, 1);
            gemm_std<<<104 * 6, 256, 0, stream>>>(
                bufB, w2T, hidden, nullptr, (ci == 0) ? b2 : nullptr, hidden,
                MROWS, CH, CH, CH, 768, 1.f, 0);
        }
    }
}